// Round 5
// baseline (144.500 us; speedup 1.0000x reference)
//
#include <hip/hip_runtime.h>
#include <hip/hip_bf16.h>
#include <stdint.h>

#define S_LEN  2048
#define EMB    1024
#define NHEAD  16
#define DK     64
#define KVB    64
#define NWAVES 4
#define QBLK   256              // 4 waves x 64 q-rows
#define NSTEPS (S_LEN/KVB)      // 32
#define QTILES (S_LEN/QBLK)     // 8
#define TILEB  8192             // one 64x64 bf16 tile, pre-swizzled
#define KVBYTES ((size_t)4*NHEAD*NSTEPS*TILEB)   // 16 MiB per tensor

typedef float  f32x4  __attribute__((ext_vector_type(4)));
typedef float  f32x16 __attribute__((ext_vector_type(16)));
typedef short  s16x8  __attribute__((ext_vector_type(8)));
typedef unsigned int u32;
typedef unsigned int u32x2 __attribute__((ext_vector_type(2)));
typedef unsigned int u32x4 __attribute__((ext_vector_type(4)));

#if __has_builtin(__builtin_amdgcn_exp2f)
#define EXP2 __builtin_amdgcn_exp2f
#else
#define EXP2 exp2f
#endif

__device__ __forceinline__ u32 cvtpk(float lo, float hi){
  u32 r;
  asm("v_cvt_pk_bf16_f32 %0, %1, %2" : "=v"(r) : "v"(lo), "v"(hi));
  return r;
}

__device__ __forceinline__ void g2l16(const void* g, void* l){
  __builtin_amdgcn_global_load_lds((const __attribute__((address_space(1))) u32*)g,
                                   (__attribute__((address_space(3))) u32*)l,
                                   16, 0, 0);
}

union FragU { u32 u[4]; s16x8 v; };

// ================== pre-pass: fp32 K/V -> bf16, pre-swizzled tiles ==================
__global__ __launch_bounds__(256)
void prep_kv(const float* __restrict__ kg, const float* __restrict__ vg,
             unsigned char* __restrict__ gK, unsigned char* __restrict__ gV)
{
  __shared__ float sv[64][68];
  const int blk = blockIdx.x;           // bh*32 + t
  const int t  = blk & 31;
  const int bh = blk >> 5;
  const int b  = bh >> 4;
  const int h  = bh & 15;
  const int tid = threadIdx.x;
  const size_t tile_off = (size_t)blk * TILEB;

  {
    const int c16 = tid & 7;
    const int kvb = tid >> 3;
    const float* kbase = kg + ((size_t)b*S_LEN + t*64)*EMB + h*DK;
    #pragma unroll
    for (int it=0; it<2; ++it){
      const int kv = kvb + it*32;
      const int d0 = 8*(c16 ^ (kv & 7));
      const float* src = kbase + (size_t)kv*EMB + d0;
      f32x4 a = *(const f32x4*)(src);
      f32x4 c = *(const f32x4*)(src + 4);
      u32x4 w;
      w.x = cvtpk(a[0],a[1]); w.y = cvtpk(a[2],a[3]);
      w.z = cvtpk(c[0],c[1]); w.w = cvtpk(c[2],c[3]);
      *(u32x4*)(gK + tile_off + kv*128 + c16*16) = w;
    }
  }

  {
    const int r  = tid >> 2;
    const int c0 = (tid & 3) * 16;
    const float* src = vg + ((size_t)b*S_LEN + t*64 + r)*EMB + h*DK + c0;
    #pragma unroll
    for (int i=0;i<4;++i) *(f32x4*)(&sv[r][c0+4*i]) = *(const f32x4*)(src + 4*i);
  }
  __syncthreads();
  {
    const int d  = tid & 63;
    const int cg = tid >> 6;
    #pragma unroll
    for (int it=0; it<2; ++it){
      const int c16 = cg + it*4;
      const int kv0 = 8*(c16 ^ (d & 7));
      u32x4 w;
      w.x = cvtpk(sv[kv0+0][d], sv[kv0+1][d]);
      w.y = cvtpk(sv[kv0+2][d], sv[kv0+3][d]);
      w.z = cvtpk(sv[kv0+4][d], sv[kv0+5][d]);
      w.w = cvtpk(sv[kv0+6][d], sv[kv0+7][d]);
      *(u32x4*)(gV + tile_off + d*128 + c16*16) = w;
    }
  }
}

// ================== main: 64 q-rows/wave, K/V frags shared across 2 subtiles ==================
__global__ __launch_bounds__(256)
void mha_main(const float* __restrict__ qg, const int* __restrict__ maskg,
              const unsigned char* __restrict__ gK, const unsigned char* __restrict__ gV,
              float* __restrict__ outg)
{
  __shared__ __align__(16) unsigned char sK [3][TILEB];   // 3-rotating K buffers
  __shared__ __align__(16) unsigned char sVt[2][TILEB];
  __shared__ float sBias[2][KVB];
  __shared__ int sAllOne;

  // XCD-chunked swizzle: 512 blocks, same-bh tiles share an XCD
  const int i0  = blockIdx.x;
  const int xcd = i0 & 7;
  const int jj0 = i0 >> 3;                 // 0..63
  const int bh  = (xcd << 3) | (jj0 >> 3); // 0..63
  const int qt  = jj0 & 7;                 // 0..7
  const int b   = bh >> 4;
  const int h   = bh & 15;

  const int tid  = threadIdx.x;
  const int lane = tid & 63;
  const int wave = tid >> 6;
  const int l31  = lane & 31;
  const int hi   = lane >> 5;

  if (tid == 0) sAllOne = 1;
  __syncthreads();
  {
    int ok = 1;
    for (int i = tid; i < S_LEN; i += 256) ok &= (maskg[(size_t)b*S_LEN + i] != 0);
    if (!ok) atomicAnd(&sAllOne, 0);
  }

  // Q fragments for both subtiles, pre-scaled by log2(e)/sqrt(d)
  const float QSCALE = 0.18033688011112042f;  // (1/8)*log2(e)
  const int qrowA = qt*QBLK + wave*64 + l31;
  const int qrowB = qrowA + 32;
  s16x8 qfA[4], qfB[4];
  {
    const float* qa = qg + ((size_t)b*S_LEN + qrowA)*EMB + h*DK + hi*8;
    const float* qc = qg + ((size_t)b*S_LEN + qrowB)*EMB + h*DK + hi*8;
    #pragma unroll
    for (int dt=0; dt<4; ++dt){
      f32x4 a0 = *(const f32x4*)(qa + dt*16);
      f32x4 a1 = *(const f32x4*)(qa + dt*16 + 4);
      f32x4 b0 = *(const f32x4*)(qc + dt*16);
      f32x4 b1 = *(const f32x4*)(qc + dt*16 + 4);
      FragU fa, fb;
      fa.u[0] = cvtpk(a0[0]*QSCALE, a0[1]*QSCALE);
      fa.u[1] = cvtpk(a0[2]*QSCALE, a0[3]*QSCALE);
      fa.u[2] = cvtpk(a1[0]*QSCALE, a1[1]*QSCALE);
      fa.u[3] = cvtpk(a1[2]*QSCALE, a1[3]*QSCALE);
      fb.u[0] = cvtpk(b0[0]*QSCALE, b0[1]*QSCALE);
      fb.u[1] = cvtpk(b0[2]*QSCALE, b0[3]*QSCALE);
      fb.u[2] = cvtpk(b1[0]*QSCALE, b1[1]*QSCALE);
      fb.u[3] = cvtpk(b1[2]*QSCALE, b1[3]*QSCALE);
      qfA[dt] = fa.v; qfB[dt] = fb.v;
    }
  }

  const unsigned char* gKt = gK + (size_t)(bh*NSTEPS)*TILEB;
  const unsigned char* gVt = gV + (size_t)(bh*NSTEPS)*TILEB;
  const int soff = wave*2048 + lane*16;

  auto stageK = [&](int buf, int t){
    const unsigned char* ks = gKt + (size_t)t*TILEB + soff;
    unsigned char* lk = &sK[buf][wave*2048];
    g2l16(ks,        lk);
    g2l16(ks + 1024, lk + 1024);
  };
  auto stageV = [&](int buf, int t){
    const unsigned char* vs = gVt + (size_t)t*TILEB + soff;
    unsigned char* lv = &sVt[buf][wave*2048];
    g2l16(vs,        lv);
    g2l16(vs + 1024, lv + 1024);
  };

  f32x16 accOA[2], accOB[2];
  #pragma unroll
  for (int mt=0;mt<2;++mt)
    #pragma unroll
    for (int r=0;r<16;++r){ accOA[mt][r] = 0.f; accOB[mt][r] = 0.f; }
  float lsumA = 0.f, lsumB = 0.f;

  __syncthreads();                 // sAllOne visibility
  const bool allone = (sAllOne != 0);

  // prologue: K(0)->buf0, K(1)->buf1, V(0)->buf0
  stageK(0, 0);
  stageK(1, 1);
  stageV(0, 0);
  if (!allone && tid < KVB)
    sBias[0][tid] = (maskg[(size_t)b*S_LEN + tid] != 0) ? 0.f : -1.0e9f;
  __syncthreads();

  const u32 kvswz = (u32)(l31 & 7) << 4;
  int kc = 0;                      // K buffer holding tile i

  for (int i=0; i<NSTEPS; ++i){
    const int vcur = i & 1;
    int ks2 = kc + 2; if (ks2 >= 3) ks2 -= 3;

    // stage ahead: K two tiles out (3rd buffer), V one tile out (other buffer)
    if (i < NSTEPS-2) stageK(ks2, i+2);
    if (i < NSTEPS-1){
      stageV(vcur^1, i+1);
      if (!allone && tid < KVB)
        sBias[vcur^1][tid] = (maskg[(size_t)b*S_LEN + (i+1)*KVB + tid] != 0) ? 0.f : -1.0e9f;
    }

    // --- K fragments once, shared by both subtiles ---
    s16x8 kf[2][4];
    #pragma unroll
    for (int h2=0;h2<2;++h2){
      const unsigned char* krow = sK[kc] + (h2*32 + l31)*128;
      #pragma unroll
      for (int dt=0;dt<4;++dt)
        kf[h2][dt] = *(const s16x8*)(krow + (((u32)(dt*32 + hi*16)) ^ kvswz));
    }

    // --- QK_A ---
    f32x16 sA[2];
    #pragma unroll
    for (int h2=0;h2<2;++h2){
      #pragma unroll
      for (int r=0;r<16;++r) sA[h2][r] = 0.f;
      #pragma unroll
      for (int dt=0;dt<4;++dt)
        sA[h2] = __builtin_amdgcn_mfma_f32_32x32x16_bf16(kf[h2][dt], qfA[dt], sA[h2], 0, 0, 0);
    }

    // --- softmax_A ---
    if (!allone){
      #pragma unroll
      for (int h2=0;h2<2;++h2)
        #pragma unroll
        for (int r=0;r<16;++r){
          const int kv = h2*32 + (r&3) + 8*(r>>2) + 4*hi;
          sA[h2][r] += sBias[vcur][kv];
        }
    }
    #pragma unroll
    for (int h2=0;h2<2;++h2)
      #pragma unroll
      for (int r=0;r<16;++r) sA[h2][r] = EXP2(sA[h2][r]);
    {
      float u8[8];
      #pragma unroll
      for (int j=0;j<8;++j)
        u8[j] = (sA[0][j] + sA[0][j+8]) + (sA[1][j] + sA[1][j+8]);
      lsumA += ((u8[0]+u8[4]) + (u8[1]+u8[5])) + ((u8[2]+u8[6]) + (u8[3]+u8[7]));
    }

    // --- pack_A ---
    s16x8 pfA[4];
    #pragma unroll
    for (int kt=0;kt<4;++kt){
      #define SCE(j) sA[(kt)>>1][((kt)&1)*8 + (j)]
      u32 x01 = cvtpk(SCE(0), SCE(1));
      u32 x23 = cvtpk(SCE(2), SCE(3));
      u32 x45 = cvtpk(SCE(4), SCE(5));
      u32 x67 = cvtpk(SCE(6), SCE(7));
      #undef SCE
      u32x2 r02 = __builtin_amdgcn_permlane32_swap(x01, x45, false, false);
      u32x2 r13 = __builtin_amdgcn_permlane32_swap(x23, x67, false, false);
      FragU f;
      f.u[0] = r02.x; f.u[1] = r13.x; f.u[2] = r02.y; f.u[3] = r13.y;
      pfA[kt] = f.v;
    }

    __builtin_amdgcn_s_setprio(1);

    // --- QK_B (reuses kf) ---
    f32x16 sB[2];
    #pragma unroll
    for (int h2=0;h2<2;++h2){
      #pragma unroll
      for (int r=0;r<16;++r) sB[h2][r] = 0.f;
      #pragma unroll
      for (int dt=0;dt<4;++dt)
        sB[h2] = __builtin_amdgcn_mfma_f32_32x32x16_bf16(kf[h2][dt], qfB[dt], sB[h2], 0, 0, 0);
    }

    // --- V fragments once, shared by both subtiles ---
    s16x8 vf[2][4];
    #pragma unroll
    for (int mt=0;mt<2;++mt){
      const unsigned char* vrp = sVt[vcur] + (mt*32 + l31)*128;
      #pragma unroll
      for (int kt=0;kt<4;++kt)
        vf[mt][kt] = *(const s16x8*)(vrp + (((u32)(kt*32 + hi*16)) ^ kvswz));
    }

    // --- PV_A (covers QK_B -> softmax_B latency) ---
    #pragma unroll
    for (int mt=0;mt<2;++mt)
      #pragma unroll
      for (int kt=0;kt<4;++kt)
        accOA[mt] = __builtin_amdgcn_mfma_f32_32x32x16_bf16(vf[mt][kt], pfA[kt], accOA[mt], 0, 0, 0);

    __builtin_amdgcn_s_setprio(0);

    // --- softmax_B ---
    if (!allone){
      #pragma unroll
      for (int h2=0;h2<2;++h2)
        #pragma unroll
        for (int r=0;r<16;++r){
          const int kv = h2*32 + (r&3) + 8*(r>>2) + 4*hi;
          sB[h2][r] += sBias[vcur][kv];
        }
    }
    #pragma unroll
    for (int h2=0;h2<2;++h2)
      #pragma unroll
      for (int r=0;r<16;++r) sB[h2][r] = EXP2(sB[h2][r]);
    {
      float u8[8];
      #pragma unroll
      for (int j=0;j<8;++j)
        u8[j] = (sB[0][j] + sB[0][j+8]) + (sB[1][j] + sB[1][j+8]);
      lsumB += ((u8[0]+u8[4]) + (u8[1]+u8[5])) + ((u8[2]+u8[6]) + (u8[3]+u8[7]));
    }

    // --- pack_B ---
    s16x8 pfB[4];
    #pragma unroll
    for (int kt=0;kt<4;++kt){
      #define SCE(j) sB[(kt)>>1][((kt)&1)*8 + (j)]
      u32 x01 = cvtpk(SCE(0), SCE(1));
      u32 x23 = cvtpk(SCE(2), SCE(3));
      u32 x45 = cvtpk(SCE(4), SCE(5));
      u32 x67 = cvtpk(SCE(6), SCE(7));
      #undef SCE
      u32x2 r02 = __builtin_amdgcn_permlane32_swap(x01, x45, false, false);
      u32x2 r13 = __builtin_amdgcn_permlane32_swap(x23, x67, false, false);
      FragU f;
      f.u[0] = r02.x; f.u[1] = r13.x; f.u[2] = r02.y; f.u[3] = r13.y;
      pfB[kt] = f.v;
    }

    // --- PV_B (reuses vf) ---
    __builtin_amdgcn_s_setprio(1);
    #pragma unroll
    for (int mt=0;mt<2;++mt)
      #pragma unroll
      for (int kt=0;kt<4;++kt)
        accOB[mt] = __builtin_amdgcn_mfma_f32_32x32x16_bf16(vf[mt][kt], pfB[kt], accOB[mt], 0, 0, 0);
    __builtin_amdgcn_s_setprio(0);

    __syncthreads();
    kc = (kc == 2) ? 0 : kc + 1;
  }

  lsumA += __shfl_xor(lsumA, 32, 64);
  lsumB += __shfl_xor(lsumB, 32, 64);
  const float invA = 1.0f / lsumA;
  const float invB = 1.0f / lsumB;
  float* oa = outg + ((size_t)b*S_LEN + qrowA)*EMB + h*DK;
  float* ob = outg + ((size_t)b*S_LEN + qrowB)*EMB + h*DK;
  #pragma unroll
  for (int mt=0;mt<2;++mt){
    #pragma unroll
    for (int u=0;u<4;++u){
      f32x4 wa, wb;
      #pragma unroll
      for (int e=0;e<4;++e){ wa[e] = accOA[mt][u*4+e]*invA; wb[e] = accOB[mt][u*4+e]*invB; }
      *(f32x4*)(oa + mt*32 + u*8 + hi*4) = wa;
      *(f32x4*)(ob + mt*32 + u*8 + hi*4) = wb;
    }
  }
}

// ================== fallback (Round-2 kernel, used if ws too small) ==================
__global__ __launch_bounds__(256)
void mha_fwd_fb(const float* __restrict__ qg, const float* __restrict__ kg,
                const float* __restrict__ vg, const int* __restrict__ maskg,
                float* __restrict__ outg)
{
  __shared__ __align__(16) unsigned char sK [2][KVB*128];
  __shared__ __align__(16) unsigned char sVt[2][DK*128];
  __shared__ float sBias[2][KVB];
  __shared__ int sAllOne;

  const int i0  = blockIdx.x;
  const int xcd = i0 & 7;
  const int jj0 = i0 >> 3;
  const int bh  = (xcd << 3) | (jj0 >> 4);
  const int qt  = jj0 & 15;
  const int b   = bh >> 4;
  const int h   = bh & 15;

  const int tid  = threadIdx.x;
  const int lane = tid & 63;
  const int wave = tid >> 6;
  const int l31  = lane & 31;
  const int hi   = lane >> 5;

  if (tid == 0) sAllOne = 1;
  __syncthreads();
  {
    int ok = 1;
    for (int i = tid; i < S_LEN; i += 256) ok &= (maskg[(size_t)b*S_LEN + i] != 0);
    if (!ok) atomicAnd(&sAllOne, 0);
  }

  const float QSCALE = 0.18033688011112042f;
  const int qrow = qt*128 + wave*32 + l31;
  const float* qb = qg + ((size_t)b*S_LEN + qrow)*EMB + h*DK + hi*8;
  s16x8 qf[4];
  #pragma unroll
  for (int dt=0; dt<4; ++dt){
    f32x4 a = *(const f32x4*)(qb + dt*16);
    f32x4 c = *(const f32x4*)(qb + dt*16 + 4);
    FragU f;
    f.u[0] = cvtpk(a[0]*QSCALE, a[1]*QSCALE);
    f.u[1] = cvtpk(a[2]*QSCALE, a[3]*QSCALE);
    f.u[2] = cvtpk(c[0]*QSCALE, c[1]*QSCALE);
    f.u[3] = cvtpk(c[2]*QSCALE, c[3]*QSCALE);
    qf[dt] = f.v;
  }

  const int srow = tid >> 2;
  const int sc4  = (tid & 3) << 4;
  const int vcg = tid & 15;
  const int vrg = tid >> 4;

  const float* kg_b = kg + (size_t)b*S_LEN*EMB + h*DK;
  const float* vg_b = vg + (size_t)b*S_LEN*EMB + h*DK;
  const float* kp0 = kg_b + (size_t)srow*EMB + sc4;
  const float* vp0 = vg_b + (size_t)(vrg*4)*EMB + vcg*4;

  f32x4 kr[4], vr[4];
  float biasr = 0.f;

  auto stage_load = [&](int t, bool needMask){
    const float* kp = kp0 + (size_t)t*(KVB*EMB);
    const float* vp = vp0 + (size_t)t*(KVB*EMB);
    #pragma unroll
    for (int i=0;i<4;++i) kr[i] = *(const f32x4*)(kp + 4*i);
    #pragma unroll
    for (int e=0;e<4;++e) vr[e] = *(const f32x4*)(vp + (size_t)e*EMB);
    if (needMask && tid < KVB)
      biasr = (maskg[(size_t)b*S_LEN + t*KVB + tid] != 0) ? 0.f : -1.0e9f;
  };

  auto stage_write = [&](int buf, bool needMask){
    unsigned char* kd = sK[buf] + srow*128;
    const u32 kswz = (u32)(srow & 7) << 4;
    u32x4 w0, w1;
    w0.x = cvtpk(kr[0][0],kr[0][1]); w0.y = cvtpk(kr[0][2],kr[0][3]);
    w0.z = cvtpk(kr[1][0],kr[1][1]); w0.w = cvtpk(kr[1][2],kr[1][3]);
    w1.x = cvtpk(kr[2][0],kr[2][1]); w1.y = cvtpk(kr[2][2],kr[2][3]);
    w1.z = cvtpk(kr[3][0],kr[3][1]); w1.w = cvtpk(kr[3][2],kr[3][3]);
    *(u32x4*)(kd + (((u32)(sc4*2))      ^ kswz)) = w0;
    *(u32x4*)(kd + (((u32)(sc4*2 + 16)) ^ kswz)) = w1;
    unsigned char* vd = sVt[buf];
    #pragma unroll
    for (int j=0;j<4;++j){
      const int d = vcg*4 + j;
      u32x2 w;
      w.x = cvtpk(vr[0][j], vr[1][j]);
      w.y = cvtpk(vr[2][j], vr[3][j]);
      const u32 swz = (u32)(((d & 7) ^ ((d >> 3) & 1)) << 4);
      *(u32x2*)(vd + d*128 + (((u32)(vrg*8)) ^ swz)) = w;
    }
    if (needMask && tid < KVB) sBias[buf][tid] = biasr;
  };

  f32x16 accO[2];
  #pragma unroll
  for (int mt=0;mt<2;++mt)
    #pragma unroll
    for (int r=0;r<16;++r) accO[mt][r] = 0.f;
  float mrun = -1.0e30f, lrun = 0.f;

  stage_load(0, true);
  stage_write(0, true);
  __syncthreads();
  const bool allone = (sAllOne != 0);

  for (int t=0; t<NSTEPS; ++t){
    const int cur = t & 1;
    if (t+1 < NSTEPS) stage_load(t+1, !allone);

    f32x16 accS[2];
    #pragma unroll
    for (int h2=0;h2<2;++h2)
      #pragma unroll
      for (int r=0;r<16;++r) accS[h2][r] = 0.f;

    const u32 kvswz = (u32)(l31 & 7) << 4;
    #pragma unroll
    for (int h2=0;h2<2;++h2){
      const unsigned char* krow = sK[cur] + (h2*32 + l31)*128;
      #pragma unroll
      for (int dt=0;dt<4;++dt){
        s16x8 kf = *(const s16x8*)(krow + (((u32)(dt*32 + hi*16)) ^ kvswz));
        accS[h2] = __builtin_amdgcn_mfma_f32_32x32x16_bf16(kf, qf[dt], accS[h2], 0, 0, 0);
      }
    }

    if (!allone){
      #pragma unroll
      for (int h2=0;h2<2;++h2)
        #pragma unroll
        for (int r=0;r<16;++r){
          const int kv = h2*32 + (r&3) + 8*(r>>2) + 4*hi;
          accS[h2][r] += sBias[cur][kv];
        }
    }

    float pmax = fmaxf(accS[0][0], accS[1][0]);
    #pragma unroll
    for (int r=1;r<16;++r) pmax = fmaxf(pmax, fmaxf(accS[0][r], accS[1][r]));
    pmax = fmaxf(pmax, __shfl_xor(pmax, 32, 64));

    if (!__all(pmax - mrun <= 8.0f)){
      const float mnew  = fmaxf(mrun, pmax);
      const float alpha = EXP2(mrun - mnew);
      lrun *= alpha;
      #pragma unroll
      for (int mt=0;mt<2;++mt)
        #pragma unroll
        for (int r=0;r<16;++r) accO[mt][r] *= alpha;
      mrun = mnew;
    }

    float rsum = 0.f;
    #pragma unroll
    for (int h2=0;h2<2;++h2)
      #pragma unroll
      for (int r=0;r<16;++r){
        float p = EXP2(accS[h2][r] - mrun);
        accS[h2][r] = p;
        rsum += p;
      }
    rsum += __shfl_xor(rsum, 32, 64);
    lrun += rsum;

    s16x8 pf[4];
    #pragma unroll
    for (int kt=0;kt<4;++kt){
      #define SCE(j) accS[(kt)>>1][((kt)&1)*8 + (j)]
      u32 x01 = cvtpk(SCE(0), SCE(1));
      u32 x23 = cvtpk(SCE(2), SCE(3));
      u32 x45 = cvtpk(SCE(4), SCE(5));
      u32 x67 = cvtpk(SCE(6), SCE(7));
      #undef SCE
      u32x2 r02 = __builtin_amdgcn_permlane32_swap(x01, x45, false, false);
      u32x2 r13 = __builtin_amdgcn_permlane32_swap(x23, x67, false, false);
      FragU f;
      f.u[0] = r02.x; f.u[1] = r13.x; f.u[2] = r02.y; f.u[3] = r13.y;
      pf[kt] = f.v;
    }

    #pragma unroll
    for (int mt=0;mt<2;++mt){
      const int vrow = mt*32 + l31;
      const u32 vswz = (u32)((((vrow & 7) ^ ((vrow >> 3) & 1))) << 4);
      const unsigned char* vrp = sVt[cur] + vrow*128;
      #pragma unroll
      for (int kt=0;kt<4;++kt){
        s16x8 vf = *(const s16x8*)(vrp + (((u32)(kt*32 + hi*16)) ^ vswz));
        accO[mt] = __builtin_amdgcn_mfma_f32_32x32x16_bf16(vf, pf[kt], accO[mt], 0, 0, 0);
      }
    }

    if (t+1 < NSTEPS) stage_write(cur^1, !allone);
    __syncthreads();
  }

  const float inv = 1.0f / lrun;
  float* ob = outg + ((size_t)b*S_LEN + qrow)*EMB + h*DK;
  #pragma unroll
  for (int mt=0;mt<2;++mt){
    #pragma unroll
    for (int u=0;u<4;++u){
      f32x4 w;
      #pragma unroll
      for (int e=0;e<4;++e) w[e] = accO[mt][u*4+e]*inv;
      *(f32x4*)(ob + mt*32 + u*8 + hi*4) = w;
    }
  }
}

extern "C" void kernel_launch(void* const* d_in, const int* in_sizes, int n_in,
                              void* d_out, int out_size, void* d_ws, size_t ws_size,
                              hipStream_t stream)
{
  const float* q    = (const float*)d_in[0];
  const float* k    = (const float*)d_in[1];
  const float* v    = (const float*)d_in[2];
  const int*   mask = (const int*)d_in[3];
  float* out = (float*)d_out;
  (void)in_sizes; (void)n_in; (void)out_size;

  if (ws_size >= 2*KVBYTES){
    unsigned char* gK = (unsigned char*)d_ws;
    unsigned char* gV = gK + KVBYTES;
    hipLaunchKernelGGL(prep_kv, dim3(4*NHEAD*NSTEPS), dim3(256), 0, stream, k, v, gK, gV);
    hipLaunchKernelGGL(mha_main, dim3(64*QTILES), dim3(256), 0, stream, q, mask, gK, gV, out);
  } else {
    hipLaunchKernelGGL(mha_fwd_fb, dim3(16*NHEAD*4), dim3(256), 0, stream, q, k, v, mask, out);
  }
}

// Round 6
// 108.912 us; speedup vs baseline: 1.3268x; 1.3268x over previous
//
#include <hip/hip_runtime.h>
#include <hip/hip_bf16.h>
#include <stdint.h>

#define S_LEN  2048
#define EMB    1024
#define NHEAD  16
#define DK     64
#define KVB    64
#define QW     32
#define NWAVES 4
#define QBLK   (QW*NWAVES)      // 128 q rows per block
#define NSTEPS (S_LEN/KVB)      // 32
#define QTILES (S_LEN/QBLK)     // 16
#define TILEB  8192             // one 64x64 bf16 tile, pre-swizzled
#define KVBYTES ((size_t)4*NHEAD*NSTEPS*TILEB)   // 16 MiB per tensor

typedef float  f32x4  __attribute__((ext_vector_type(4)));
typedef float  f32x16 __attribute__((ext_vector_type(16)));
typedef short  s16x8  __attribute__((ext_vector_type(8)));
typedef unsigned int u32;
typedef unsigned int u32x2 __attribute__((ext_vector_type(2)));
typedef unsigned int u32x4 __attribute__((ext_vector_type(4)));

#if __has_builtin(__builtin_amdgcn_exp2f)
#define EXP2 __builtin_amdgcn_exp2f
#else
#define EXP2 exp2f
#endif

#define WAITVM(N) asm volatile("s_waitcnt vmcnt(" #N ")" ::: "memory")
#define WAITLG0() asm volatile("s_waitcnt lgkmcnt(0)" ::: "memory")

__device__ __forceinline__ u32 cvtpk(float lo, float hi){
  u32 r;
  asm("v_cvt_pk_bf16_f32 %0, %1, %2" : "=v"(r) : "v"(lo), "v"(hi));
  return r;
}

__device__ __forceinline__ void g2l16(const void* g, void* l){
  __builtin_amdgcn_global_load_lds((const __attribute__((address_space(1))) u32*)g,
                                   (__attribute__((address_space(3))) u32*)l,
                                   16, 0, 0);
}

union FragU { u32 u[4]; s16x8 v; };

// ================== pre-pass: fp32 K/V -> bf16, pre-swizzled tiles ==================
__global__ __launch_bounds__(256)
void prep_kv(const float* __restrict__ kg, const float* __restrict__ vg,
             unsigned char* __restrict__ gK, unsigned char* __restrict__ gV)
{
  __shared__ float sv[64][68];
  const int blk = blockIdx.x;           // bh*32 + t
  const int t  = blk & 31;
  const int bh = blk >> 5;
  const int b  = bh >> 4;
  const int h  = bh & 15;
  const int tid = threadIdx.x;
  const size_t tile_off = (size_t)blk * TILEB;

  {
    const int c16 = tid & 7;
    const int kvb = tid >> 3;
    const float* kbase = kg + ((size_t)b*S_LEN + t*64)*EMB + h*DK;
    #pragma unroll
    for (int it=0; it<2; ++it){
      const int kv = kvb + it*32;
      const int d0 = 8*(c16 ^ (kv & 7));
      const float* src = kbase + (size_t)kv*EMB + d0;
      f32x4 a = *(const f32x4*)(src);
      f32x4 c = *(const f32x4*)(src + 4);
      u32x4 w;
      w.x = cvtpk(a[0],a[1]); w.y = cvtpk(a[2],a[3]);
      w.z = cvtpk(c[0],c[1]); w.w = cvtpk(c[2],c[3]);
      *(u32x4*)(gK + tile_off + kv*128 + c16*16) = w;
    }
  }

  {
    const int r  = tid >> 2;
    const int c0 = (tid & 3) * 16;
    const float* src = vg + ((size_t)b*S_LEN + t*64 + r)*EMB + h*DK + c0;
    #pragma unroll
    for (int i=0;i<4;++i) *(f32x4*)(&sv[r][c0+4*i]) = *(const f32x4*)(src + 4*i);
  }
  __syncthreads();
  {
    const int d  = tid & 63;
    const int cg = tid >> 6;
    #pragma unroll
    for (int it=0; it<2; ++it){
      const int c16 = cg + it*4;
      const int kv0 = 8*(c16 ^ (d & 7));
      u32x4 w;
      w.x = cvtpk(sv[kv0+0][d], sv[kv0+1][d]);
      w.y = cvtpk(sv[kv0+2][d], sv[kv0+3][d]);
      w.z = cvtpk(sv[kv0+4][d], sv[kv0+5][d]);
      w.w = cvtpk(sv[kv0+6][d], sv[kv0+7][d]);
      *(u32x4*)(gV + tile_off + d*128 + c16*16) = w;
    }
  }
}

// ================== main: pipelined flash attention, counted-vmcnt barriers ==================
__global__ __launch_bounds__(256)
void mha_main(const float* __restrict__ qg, const int* __restrict__ maskg,
              const unsigned char* __restrict__ gK, const unsigned char* __restrict__ gV,
              float* __restrict__ outg)
{
  __shared__ __align__(16) unsigned char sK [2][TILEB];
  __shared__ __align__(16) unsigned char sVt[2][TILEB];
  __shared__ float sBias[2][KVB];
  __shared__ int sAllOne;

  const int i0  = blockIdx.x;
  const int xcd = i0 & 7;
  const int jj0 = i0 >> 3;
  const int bh  = (xcd << 3) | (jj0 >> 4);
  const int qt  = jj0 & 15;
  const int b   = bh >> 4;
  const int h   = bh & 15;

  const int tid  = threadIdx.x;
  const int lane = tid & 63;
  const int wave = tid >> 6;
  const int l31  = lane & 31;
  const int hi   = lane >> 5;

  if (tid == 0) sAllOne = 1;
  __syncthreads();
  {
    int ok = 1;
    for (int i = tid; i < S_LEN; i += 256) ok &= (maskg[(size_t)b*S_LEN + i] != 0);
    if (!ok) atomicAnd(&sAllOne, 0);
  }

  // Q fragments, pre-scaled by log2(e)/sqrt(d)
  const float QSCALE = 0.18033688011112042f;  // (1/8)*log2(e)
  const int qrow = qt*QBLK + wave*QW + l31;
  const float* qb = qg + ((size_t)b*S_LEN + qrow)*EMB + h*DK + hi*8;
  s16x8 qf[4];
  #pragma unroll
  for (int dt=0; dt<4; ++dt){
    f32x4 a = *(const f32x4*)(qb + dt*16);
    f32x4 c = *(const f32x4*)(qb + dt*16 + 4);
    FragU f;
    f.u[0] = cvtpk(a[0]*QSCALE, a[1]*QSCALE);
    f.u[1] = cvtpk(a[2]*QSCALE, a[3]*QSCALE);
    f.u[2] = cvtpk(c[0]*QSCALE, c[1]*QSCALE);
    f.u[3] = cvtpk(c[2]*QSCALE, c[3]*QSCALE);
    qf[dt] = f.v;
  }

  const unsigned char* gKt = gK + (size_t)(bh*NSTEPS)*TILEB;
  const unsigned char* gVt = gV + (size_t)(bh*NSTEPS)*TILEB;
  const int soff = wave*2048 + lane*16;

  auto stageK = [&](int buf, int t){
    const unsigned char* ks = gKt + (size_t)t*TILEB + soff;
    unsigned char* lk = &sK[buf][wave*2048];
    g2l16(ks,        lk);
    g2l16(ks + 1024, lk + 1024);
  };
  auto stageV = [&](int buf, int t){
    const unsigned char* vs = gVt + (size_t)t*TILEB + soff;
    unsigned char* lv = &sVt[buf][wave*2048];
    g2l16(vs,        lv);
    g2l16(vs + 1024, lv + 1024);
  };

  f32x16 accO[2];
  #pragma unroll
  for (int mt=0;mt<2;++mt)
    #pragma unroll
    for (int r=0;r<16;++r) accO[mt][r] = 0.f;
  float lsum = 0.f;

  __syncthreads();                 // sAllOne visibility
  const bool allone = (sAllOne != 0);

  // prologue: K(0),K(1),V(0) staged; QK(0) computed
  stageK(0, 0);
  stageK(1, 1);
  stageV(0, 0);
  if (!allone && tid < KVB)
    sBias[0][tid] = (maskg[(size_t)b*S_LEN + tid] != 0) ? 0.f : -1.0e9f;
  __syncthreads();                 // full drain once (outside hot loop)

  const u32 kvswz = (u32)(l31 & 7) << 4;
  f32x16 accS[2];

  {
    #pragma unroll
    for (int h2=0;h2<2;++h2){
      #pragma unroll
      for (int r=0;r<16;++r) accS[h2][r] = 0.f;
      const unsigned char* krow = sK[0] + (h2*32 + l31)*128;
      #pragma unroll
      for (int dt=0;dt<4;++dt){
        s16x8 kf = *(const s16x8*)(krow + (((u32)(dt*32 + hi*16)) ^ kvswz));
        accS[h2] = __builtin_amdgcn_mfma_f32_32x32x16_bf16(kf, qf[dt], accS[h2], 0, 0, 0);
      }
    }
  }
  // QK(0)'s ds_reads retired before iter-0 overwrites sK[0]
  WAITLG0();
  __builtin_amdgcn_s_barrier();

  for (int i=0; i<NSTEPS; ++i){
    const int cur = i & 1;
    const int nxt = cur ^ 1;

    // (1) issue stages: K two tiles out, V one tile out — land under compute,
    //     NOT drained this iteration (counted vmcnt below)
    if (i < NSTEPS-2) stageK(cur, i+2);
    if (i < NSTEPS-1){
      stageV(nxt, i+1);
      if (!allone && tid < KVB)
        sBias[nxt][tid] = (maskg[(size_t)b*S_LEN + (i+1)*KVB + tid] != 0) ? 0.f : -1.0e9f;
    }

    // (2) drain only PREVIOUS iter's loads (K(i+1), V(i) quarters), publish
    if (i < NSTEPS-2)      { WAITVM(4); }
    else if (i < NSTEPS-1) { WAITVM(2); }
    else                   { WAITVM(0); }
    __builtin_amdgcn_s_barrier();

    // (3) softmax(i): bias, exp2, tree-sum
    if (!allone){
      #pragma unroll
      for (int h2=0;h2<2;++h2)
        #pragma unroll
        for (int r=0;r<16;++r){
          const int kv = h2*32 + (r&3) + 8*(r>>2) + 4*hi;
          accS[h2][r] += sBias[cur][kv];
        }
    }
    #pragma unroll
    for (int h2=0;h2<2;++h2)
      #pragma unroll
      for (int r=0;r<16;++r)
        accS[h2][r] = EXP2(accS[h2][r]);

    {
      float u8[8];
      #pragma unroll
      for (int j=0;j<8;++j)
        u8[j] = (accS[0][j] + accS[0][j+8]) + (accS[1][j] + accS[1][j+8]);
      float x0 = (u8[0]+u8[4]) + (u8[1]+u8[5]);
      float x1 = (u8[2]+u8[6]) + (u8[3]+u8[7]);
      lsum += x0 + x1;
    }

    // (4) pack(i): 16 cvt_pk + 8 permlane32_swap
    s16x8 pf[4];
    #pragma unroll
    for (int kt=0;kt<4;++kt){
      #define SCE(j) accS[(kt)>>1][((kt)&1)*8 + (j)]
      u32 x01 = cvtpk(SCE(0), SCE(1));
      u32 x23 = cvtpk(SCE(2), SCE(3));
      u32 x45 = cvtpk(SCE(4), SCE(5));
      u32 x67 = cvtpk(SCE(6), SCE(7));
      #undef SCE
      u32x2 r02 = __builtin_amdgcn_permlane32_swap(x01, x45, false, false);
      u32x2 r13 = __builtin_amdgcn_permlane32_swap(x23, x67, false, false);
      FragU f;
      f.u[0] = r02.x; f.u[1] = r13.x; f.u[2] = r02.y; f.u[3] = r13.y;
      pf[kt] = f.v;
    }

    __builtin_amdgcn_s_setprio(1);

    // (5) QK(i+1) into accS (overlaps softmax/pack VALU of this iter)
    if (i < NSTEPS-1){
      #pragma unroll
      for (int h2=0;h2<2;++h2){
        #pragma unroll
        for (int r=0;r<16;++r) accS[h2][r] = 0.f;
        const unsigned char* krow = sK[nxt] + (h2*32 + l31)*128;
        #pragma unroll
        for (int dt=0;dt<4;++dt){
          s16x8 kf = *(const s16x8*)(krow + (((u32)(dt*32 + hi*16)) ^ kvswz));
          accS[h2] = __builtin_amdgcn_mfma_f32_32x32x16_bf16(kf, qf[dt], accS[h2], 0, 0, 0);
        }
      }
    }

    // (6) PV(i)
    #pragma unroll
    for (int mt=0;mt<2;++mt){
      const unsigned char* vrp = sVt[cur] + (mt*32 + l31)*128;
      #pragma unroll
      for (int kt=0;kt<4;++kt){
        s16x8 vf = *(const s16x8*)(vrp + (((u32)(kt*32 + hi*16)) ^ kvswz));
        accO[mt] = __builtin_amdgcn_mfma_f32_32x32x16_bf16(vf, pf[kt], accO[mt], 0, 0, 0);
      }
    }

    __builtin_amdgcn_s_setprio(0);

    // (7) all this iter's LDS reads retired -> next iter may overwrite buffers
    WAITLG0();
    __builtin_amdgcn_s_barrier();
  }

  lsum += __shfl_xor(lsum, 32, 64);
  const float inv = 1.0f / lsum;
  float* ob = outg + ((size_t)b*S_LEN + qrow)*EMB + h*DK;
  #pragma unroll
  for (int mt=0;mt<2;++mt){
    #pragma unroll
    for (int u=0;u<4;++u){
      f32x4 w;
      #pragma unroll
      for (int e=0;e<4;++e) w[e] = accO[mt][u*4+e]*inv;
      *(f32x4*)(ob + mt*32 + u*8 + hi*4) = w;
    }
  }
}

// ================== fallback (Round-2 kernel, used if ws too small) ==================
__global__ __launch_bounds__(256)
void mha_fwd_fb(const float* __restrict__ qg, const float* __restrict__ kg,
                const float* __restrict__ vg, const int* __restrict__ maskg,
                float* __restrict__ outg)
{
  __shared__ __align__(16) unsigned char sK [2][KVB*128];
  __shared__ __align__(16) unsigned char sVt[2][DK*128];
  __shared__ float sBias[2][KVB];
  __shared__ int sAllOne;

  const int i0  = blockIdx.x;
  const int xcd = i0 & 7;
  const int jj0 = i0 >> 3;
  const int bh  = (xcd << 3) | (jj0 >> 4);
  const int qt  = jj0 & 15;
  const int b   = bh >> 4;
  const int h   = bh & 15;

  const int tid  = threadIdx.x;
  const int lane = tid & 63;
  const int wave = tid >> 6;
  const int l31  = lane & 31;
  const int hi   = lane >> 5;

  if (tid == 0) sAllOne = 1;
  __syncthreads();
  {
    int ok = 1;
    for (int i = tid; i < S_LEN; i += 256) ok &= (maskg[(size_t)b*S_LEN + i] != 0);
    if (!ok) atomicAnd(&sAllOne, 0);
  }

  const float QSCALE = 0.18033688011112042f;
  const int qrow = qt*128 + wave*32 + l31;
  const float* qb = qg + ((size_t)b*S_LEN + qrow)*EMB + h*DK + hi*8;
  s16x8 qf[4];
  #pragma unroll
  for (int dt=0; dt<4; ++dt){
    f32x4 a = *(const f32x4*)(qb + dt*16);
    f32x4 c = *(const f32x4*)(qb + dt*16 + 4);
    FragU f;
    f.u[0] = cvtpk(a[0]*QSCALE, a[1]*QSCALE);
    f.u[1] = cvtpk(a[2]*QSCALE, a[3]*QSCALE);
    f.u[2] = cvtpk(c[0]*QSCALE, c[1]*QSCALE);
    f.u[3] = cvtpk(c[2]*QSCALE, c[3]*QSCALE);
    qf[dt] = f.v;
  }

  const int srow = tid >> 2;
  const int sc4  = (tid & 3) << 4;
  const int vcg = tid & 15;
  const int vrg = tid >> 4;

  const float* kg_b = kg + (size_t)b*S_LEN*EMB + h*DK;
  const float* vg_b = vg + (size_t)b*S_LEN*EMB + h*DK;
  const float* kp0 = kg_b + (size_t)srow*EMB + sc4;
  const float* vp0 = vg_b + (size_t)(vrg*4)*EMB + vcg*4;

  f32x4 kr[4], vr[4];
  float biasr = 0.f;

  auto stage_load = [&](int t, bool needMask){
    const float* kp = kp0 + (size_t)t*(KVB*EMB);
    const float* vp = vp0 + (size_t)t*(KVB*EMB);
    #pragma unroll
    for (int i=0;i<4;++i) kr[i] = *(const f32x4*)(kp + 4*i);
    #pragma unroll
    for (int e=0;e<4;++e) vr[e] = *(const f32x4*)(vp + (size_t)e*EMB);
    if (needMask && tid < KVB)
      biasr = (maskg[(size_t)b*S_LEN + t*KVB + tid] != 0) ? 0.f : -1.0e9f;
  };

  auto stage_write = [&](int buf, bool needMask){
    unsigned char* kd = sK[buf] + srow*128;
    const u32 kswz = (u32)(srow & 7) << 4;
    u32x4 w0, w1;
    w0.x = cvtpk(kr[0][0],kr[0][1]); w0.y = cvtpk(kr[0][2],kr[0][3]);
    w0.z = cvtpk(kr[1][0],kr[1][1]); w0.w = cvtpk(kr[1][2],kr[1][3]);
    w1.x = cvtpk(kr[2][0],kr[2][1]); w1.y = cvtpk(kr[2][2],kr[2][3]);
    w1.z = cvtpk(kr[3][0],kr[3][1]); w1.w = cvtpk(kr[3][2],kr[3][3]);
    *(u32x4*)(kd + (((u32)(sc4*2))      ^ kswz)) = w0;
    *(u32x4*)(kd + (((u32)(sc4*2 + 16)) ^ kswz)) = w1;
    unsigned char* vd = sVt[buf];
    #pragma unroll
    for (int j=0;j<4;++j){
      const int d = vcg*4 + j;
      u32x2 w;
      w.x = cvtpk(vr[0][j], vr[1][j]);
      w.y = cvtpk(vr[2][j], vr[3][j]);
      const u32 swz = (u32)(((d & 7) ^ ((d >> 3) & 1)) << 4);
      *(u32x2*)(vd + d*128 + (((u32)(vrg*8)) ^ swz)) = w;
    }
    if (needMask && tid < KVB) sBias[buf][tid] = biasr;
  };

  f32x16 accO[2];
  #pragma unroll
  for (int mt=0;mt<2;++mt)
    #pragma unroll
    for (int r=0;r<16;++r) accO[mt][r] = 0.f;
  float mrun = -1.0e30f, lrun = 0.f;

  stage_load(0, true);
  stage_write(0, true);
  __syncthreads();
  const bool allone = (sAllOne != 0);

  for (int t=0; t<NSTEPS; ++t){
    const int cur = t & 1;
    if (t+1 < NSTEPS) stage_load(t+1, !allone);

    f32x16 accS[2];
    #pragma unroll
    for (int h2=0;h2<2;++h2)
      #pragma unroll
      for (int r=0;r<16;++r) accS[h2][r] = 0.f;

    const u32 kvswz = (u32)(l31 & 7) << 4;
    #pragma unroll
    for (int h2=0;h2<2;++h2){
      const unsigned char* krow = sK[cur] + (h2*32 + l31)*128;
      #pragma unroll
      for (int dt=0;dt<4;++dt){
        s16x8 kf = *(const s16x8*)(krow + (((u32)(dt*32 + hi*16)) ^ kvswz));
        accS[h2] = __builtin_amdgcn_mfma_f32_32x32x16_bf16(kf, qf[dt], accS[h2], 0, 0, 0);
      }
    }

    if (!allone){
      #pragma unroll
      for (int h2=0;h2<2;++h2)
        #pragma unroll
        for (int r=0;r<16;++r){
          const int kv = h2*32 + (r&3) + 8*(r>>2) + 4*hi;
          accS[h2][r] += sBias[cur][kv];
        }
    }

    float pmax = fmaxf(accS[0][0], accS[1][0]);
    #pragma unroll
    for (int r=1;r<16;++r) pmax = fmaxf(pmax, fmaxf(accS[0][r], accS[1][r]));
    pmax = fmaxf(pmax, __shfl_xor(pmax, 32, 64));

    if (!__all(pmax - mrun <= 8.0f)){
      const float mnew  = fmaxf(mrun, pmax);
      const float alpha = EXP2(mrun - mnew);
      lrun *= alpha;
      #pragma unroll
      for (int mt=0;mt<2;++mt)
        #pragma unroll
        for (int r=0;r<16;++r) accO[mt][r] *= alpha;
      mrun = mnew;
    }

    float rsum = 0.f;
    #pragma unroll
    for (int h2=0;h2<2;++h2)
      #pragma unroll
      for (int r=0;r<16;++r){
        float p = EXP2(accS[h2][r] - mrun);
        accS[h2][r] = p;
        rsum += p;
      }
    rsum += __shfl_xor(rsum, 32, 64);
    lrun += rsum;

    s16x8 pf[4];
    #pragma unroll
    for (int kt=0;kt<4;++kt){
      #define SCE(j) accS[(kt)>>1][((kt)&1)*8 + (j)]
      u32 x01 = cvtpk(SCE(0), SCE(1));
      u32 x23 = cvtpk(SCE(2), SCE(3));
      u32 x45 = cvtpk(SCE(4), SCE(5));
      u32 x67 = cvtpk(SCE(6), SCE(7));
      #undef SCE
      u32x2 r02 = __builtin_amdgcn_permlane32_swap(x01, x45, false, false);
      u32x2 r13 = __builtin_amdgcn_permlane32_swap(x23, x67, false, false);
      FragU f;
      f.u[0] = r02.x; f.u[1] = r13.x; f.u[2] = r02.y; f.u[3] = r13.y;
      pf[kt] = f.v;
    }

    #pragma unroll
    for (int mt=0;mt<2;++mt){
      const int vrow = mt*32 + l31;
      const u32 vswz = (u32)((((vrow & 7) ^ ((vrow >> 3) & 1))) << 4);
      const unsigned char* vrp = sVt[cur] + vrow*128;
      #pragma unroll
      for (int kt=0;kt<4;++kt){
        s16x8 vf = *(const s16x8*)(vrp + (((u32)(kt*32 + hi*16)) ^ vswz));
        accO[mt] = __builtin_amdgcn_mfma_f32_32x32x16_bf16(vf, pf[kt], accO[mt], 0, 0, 0);
      }
    }

    if (t+1 < NSTEPS) stage_write(cur^1, !allone);
    __syncthreads();
  }

  const float inv = 1.0f / lrun;
  float* ob = outg + ((size_t)b*S_LEN + qrow)*EMB + h*DK;
  #pragma unroll
  for (int mt=0;mt<2;++mt){
    #pragma unroll
    for (int u=0;u<4;++u){
      f32x4 w;
      #pragma unroll
      for (int e=0;e<4;++e) w[e] = accO[mt][u*4+e]*inv;
      *(f32x4*)(ob + mt*32 + u*8 + hi*4) = w;
    }
  }
}

extern "C" void kernel_launch(void* const* d_in, const int* in_sizes, int n_in,
                              void* d_out, int out_size, void* d_ws, size_t ws_size,
                              hipStream_t stream)
{
  const float* q    = (const float*)d_in[0];
  const float* k    = (const float*)d_in[1];
  const float* v    = (const float*)d_in[2];
  const int*   mask = (const int*)d_in[3];
  float* out = (float*)d_out;
  (void)in_sizes; (void)n_in; (void)out_size;

  if (ws_size >= 2*KVBYTES){
    unsigned char* gK = (unsigned char*)d_ws;
    unsigned char* gV = gK + KVBYTES;
    hipLaunchKernelGGL(prep_kv, dim3(4*NHEAD*NSTEPS), dim3(256), 0, stream, k, v, gK, gV);
    hipLaunchKernelGGL(mha_main, dim3(64*QTILES), dim3(256), 0, stream, q, mask, gK, gV, out);
  } else {
    hipLaunchKernelGGL(mha_fwd_fb, dim3(64*QTILES), dim3(256), 0, stream, q, k, v, mask, out);
  }
}

// Round 7
// 107.164 us; speedup vs baseline: 1.3484x; 1.0163x over previous
//
#include <hip/hip_runtime.h>
#include <hip/hip_bf16.h>
#include <stdint.h>

#define S_LEN  2048
#define EMB    1024
#define NHEAD  16
#define DK     64
#define KVB    64
#define QW     32
#define NWAVES 4
#define QBLK   (QW*NWAVES)      // 128 q rows per block
#define NSTEPS (S_LEN/KVB)      // 32
#define QTILES (S_LEN/QBLK)     // 16
#define TILEB  8192             // one 64x64 bf16 tile, fragment-linear order
#define KVBYTES ((size_t)4*NHEAD*NSTEPS*TILEB)   // 16 MiB per tensor

typedef float  f32x4  __attribute__((ext_vector_type(4)));
typedef float  f32x16 __attribute__((ext_vector_type(16)));
typedef short  s16x8  __attribute__((ext_vector_type(8)));
typedef unsigned int u32;
typedef unsigned int u32x2 __attribute__((ext_vector_type(2)));
typedef unsigned int u32x4 __attribute__((ext_vector_type(4)));

#if __has_builtin(__builtin_amdgcn_exp2f)
#define EXP2 __builtin_amdgcn_exp2f
#else
#define EXP2 exp2f
#endif

#define WAITVM(N) asm volatile("s_waitcnt vmcnt(" #N ")" ::: "memory")
#define WAITLG0() asm volatile("s_waitcnt lgkmcnt(0)" ::: "memory")

__device__ __forceinline__ u32 cvtpk(float lo, float hi){
  u32 r;
  asm("v_cvt_pk_bf16_f32 %0, %1, %2" : "=v"(r) : "v"(lo), "v"(hi));
  return r;
}

__device__ __forceinline__ void g2l16(const void* g, void* l){
  __builtin_amdgcn_global_load_lds((const __attribute__((address_space(1))) u32*)g,
                                   (__attribute__((address_space(3))) u32*)l,
                                   16, 0, 0);
}

union FragU { u32 u[4]; s16x8 v; };

// ============ pre-pass: fp32 K/V -> bf16 tiles in FRAGMENT-LINEAR order ============
// Tile byte layout (per 64x64 tile, 8 KB):  offset = fr*1024 + lane*16
//   K tile: fr=(h2*4+dt): bf16 K[t*64 + h2*32 + (lane&31)][dt*16 + (lane>>5)*8 + j]
//   V tile: fr=(mt*4+kt): bf16 V[t*64 + kt*16 + (lane>>5)*8 + j][mt*32 + (lane&31)]
// Main kernel then reads each fragment as 64 consecutive 16B chunks: stride-1,
// conflict-free, one base vaddr + immediate offsets.
__global__ __launch_bounds__(256)
void prep_kv(const float* __restrict__ kg, const float* __restrict__ vg,
             unsigned char* __restrict__ gK, unsigned char* __restrict__ gV)
{
  __shared__ float sv[64][68];
  const int blk = blockIdx.x;           // bh*32 + t
  const int t  = blk & 31;
  const int bh = blk >> 5;
  const int b  = bh >> 4;
  const int h  = bh & 15;
  const int tid  = threadIdx.x;
  const int lane = tid & 63;
  const int frq  = tid >> 6;            // 0..3
  const size_t tile_off = (size_t)blk * TILEB;

  // K: read 32B per thread from one row, write 16B fragment-linear (coalesced)
  {
    const float* kbase = kg + ((size_t)b*S_LEN + t*64)*EMB + h*DK;
    #pragma unroll
    for (int it=0; it<2; ++it){
      const int fr  = frq + it*4;
      const int row = (fr>>2)*32 + (lane&31);
      const int col = (fr&3)*16 + ((lane>>5)&1)*8;
      const float* src = kbase + (size_t)row*EMB + col;
      f32x4 a = *(const f32x4*)(src);
      f32x4 c = *(const f32x4*)(src + 4);
      u32x4 w;
      w.x = cvtpk(a[0],a[1]); w.y = cvtpk(a[2],a[3]);
      w.z = cvtpk(c[0],c[1]); w.w = cvtpk(c[2],c[3]);
      *(u32x4*)(gK + tile_off + fr*1024 + lane*16) = w;
    }
  }

  // V: stage tile into LDS (coalesced reads), then transpose out fragment-linear
  {
    const int r  = tid >> 2;
    const int c0 = (tid & 3) * 16;
    const float* src = vg + ((size_t)b*S_LEN + t*64 + r)*EMB + h*DK + c0;
    #pragma unroll
    for (int i=0;i<4;++i) *(f32x4*)(&sv[r][c0+4*i]) = *(const f32x4*)(src + 4*i);
  }
  __syncthreads();
  {
    #pragma unroll
    for (int it=0; it<2; ++it){
      const int fr  = frq + it*4;
      const int d   = (fr>>2)*32 + (lane&31);
      const int kv0 = (fr&3)*16 + ((lane>>5)&1)*8;
      u32x4 w;
      w.x = cvtpk(sv[kv0+0][d], sv[kv0+1][d]);
      w.y = cvtpk(sv[kv0+2][d], sv[kv0+3][d]);
      w.z = cvtpk(sv[kv0+4][d], sv[kv0+5][d]);
      w.w = cvtpk(sv[kv0+6][d], sv[kv0+7][d]);
      *(u32x4*)(gV + tile_off + fr*1024 + lane*16) = w;
    }
  }
}

// ================== main: pipelined flash attention, fragment-linear LDS ==================
__global__ __launch_bounds__(256)
void mha_main(const float* __restrict__ qg, const int* __restrict__ maskg,
              const unsigned char* __restrict__ gK, const unsigned char* __restrict__ gV,
              float* __restrict__ outg)
{
  __shared__ __align__(16) unsigned char sK [2][TILEB];
  __shared__ __align__(16) unsigned char sVt[2][TILEB];
  __shared__ float sBias[2][KVB];
  __shared__ int sAllOne;

  const int i0  = blockIdx.x;
  const int xcd = i0 & 7;
  const int jj0 = i0 >> 3;
  const int bh  = (xcd << 3) | (jj0 >> 4);
  const int qt  = jj0 & 15;
  const int b   = bh >> 4;
  const int h   = bh & 15;

  const int tid  = threadIdx.x;
  const int lane = tid & 63;
  const int wave = tid >> 6;
  const int l31  = lane & 31;
  const int hi   = lane >> 5;

  if (tid == 0) sAllOne = 1;
  __syncthreads();
  {
    int ok = 1;
    for (int i = tid; i < S_LEN; i += 256) ok &= (maskg[(size_t)b*S_LEN + i] != 0);
    if (!ok) atomicAnd(&sAllOne, 0);
  }

  // Q fragments, pre-scaled by log2(e)/sqrt(d)
  const float QSCALE = 0.18033688011112042f;  // (1/8)*log2(e)
  const int qrow = qt*QBLK + wave*QW + l31;
  const float* qb = qg + ((size_t)b*S_LEN + qrow)*EMB + h*DK + hi*8;
  s16x8 qf[4];
  #pragma unroll
  for (int dt=0; dt<4; ++dt){
    f32x4 a = *(const f32x4*)(qb + dt*16);
    f32x4 c = *(const f32x4*)(qb + dt*16 + 4);
    FragU f;
    f.u[0] = cvtpk(a[0]*QSCALE, a[1]*QSCALE);
    f.u[1] = cvtpk(a[2]*QSCALE, a[3]*QSCALE);
    f.u[2] = cvtpk(c[0]*QSCALE, c[1]*QSCALE);
    f.u[3] = cvtpk(c[2]*QSCALE, c[3]*QSCALE);
    qf[dt] = f.v;
  }

  const unsigned char* gKt = gK + (size_t)(bh*NSTEPS)*TILEB;
  const unsigned char* gVt = gV + (size_t)(bh*NSTEPS)*TILEB;
  const int soff = wave*2048 + lane*16;

  auto stageK = [&](int buf, int t){
    const unsigned char* ks = gKt + (size_t)t*TILEB + soff;
    unsigned char* lk = &sK[buf][wave*2048];
    g2l16(ks,        lk);
    g2l16(ks + 1024, lk + 1024);
  };
  auto stageV = [&](int buf, int t){
    const unsigned char* vs = gVt + (size_t)t*TILEB + soff;
    unsigned char* lv = &sVt[buf][wave*2048];
    g2l16(vs,        lv);
    g2l16(vs + 1024, lv + 1024);
  };

  // loop-invariant fragment read bases (one vaddr; fragments via immediate offsets)
  const unsigned char* kb0 = sK[0]  + lane*16;
  const unsigned char* kb1 = sK[1]  + lane*16;
  const unsigned char* vb0 = sVt[0] + lane*16;
  const unsigned char* vb1 = sVt[1] + lane*16;

  f32x16 accO[2];
  #pragma unroll
  for (int mt=0;mt<2;++mt)
    #pragma unroll
    for (int r=0;r<16;++r) accO[mt][r] = 0.f;
  float lsum = 0.f;

  // persistent zero C-operand (saves 32 acc-zero movs per iter)
  f32x16 z16;
  #pragma unroll
  for (int r=0;r<16;++r) z16[r] = 0.f;

  __syncthreads();                 // sAllOne visibility
  const bool allone = (sAllOne != 0);

  // prologue: K(0),K(1),V(0) staged; QK(0) computed
  stageK(0, 0);
  stageK(1, 1);
  stageV(0, 0);
  if (!allone && tid < KVB)
    sBias[0][tid] = (maskg[(size_t)b*S_LEN + tid] != 0) ? 0.f : -1.0e9f;
  __syncthreads();                 // full drain once (outside hot loop)

  f32x16 accS[2];
  {
    #pragma unroll
    for (int h2=0;h2<2;++h2){
      accS[h2] = __builtin_amdgcn_mfma_f32_32x32x16_bf16(
                   *(const s16x8*)(kb0 + (h2*4+0)*1024), qf[0], z16, 0, 0, 0);
      #pragma unroll
      for (int dt=1;dt<4;++dt)
        accS[h2] = __builtin_amdgcn_mfma_f32_32x32x16_bf16(
                     *(const s16x8*)(kb0 + (h2*4+dt)*1024), qf[dt], accS[h2], 0, 0, 0);
    }
  }
  WAITLG0();
  __builtin_amdgcn_s_barrier();

  for (int i=0; i<NSTEPS; ++i){
    const int cur = i & 1;
    const int nxt = cur ^ 1;
    const unsigned char* kbn = nxt ? kb1 : kb0;
    const unsigned char* vbc = cur ? vb1 : vb0;

    // (1) issue stages: K two tiles out, V one tile out (counted vmcnt below)
    if (i < NSTEPS-2) stageK(cur, i+2);
    if (i < NSTEPS-1){
      stageV(nxt, i+1);
      if (!allone && tid < KVB)
        sBias[nxt][tid] = (maskg[(size_t)b*S_LEN + (i+1)*KVB + tid] != 0) ? 0.f : -1.0e9f;
    }

    // (2) drain only PREVIOUS iter's loads, publish
    if (i < NSTEPS-2)      { WAITVM(4); }
    else if (i < NSTEPS-1) { WAITVM(2); }
    else                   { WAITVM(0); }
    __builtin_amdgcn_s_barrier();

    // (3) softmax(i): bias, exp2, tree-sum
    if (!allone){
      #pragma unroll
      for (int h2=0;h2<2;++h2)
        #pragma unroll
        for (int r=0;r<16;++r){
          const int kv = h2*32 + (r&3) + 8*(r>>2) + 4*hi;
          accS[h2][r] += sBias[cur][kv];
        }
    }
    #pragma unroll
    for (int h2=0;h2<2;++h2)
      #pragma unroll
      for (int r=0;r<16;++r)
        accS[h2][r] = EXP2(accS[h2][r]);

    {
      float u8[8];
      #pragma unroll
      for (int j=0;j<8;++j)
        u8[j] = (accS[0][j] + accS[0][j+8]) + (accS[1][j] + accS[1][j+8]);
      float x0 = (u8[0]+u8[4]) + (u8[1]+u8[5]);
      float x1 = (u8[2]+u8[6]) + (u8[3]+u8[7]);
      lsum += x0 + x1;
    }

    // (4) pack(i): 16 cvt_pk + 8 permlane32_swap
    s16x8 pf[4];
    #pragma unroll
    for (int kt=0;kt<4;++kt){
      #define SCE(j) accS[(kt)>>1][((kt)&1)*8 + (j)]
      u32 x01 = cvtpk(SCE(0), SCE(1));
      u32 x23 = cvtpk(SCE(2), SCE(3));
      u32 x45 = cvtpk(SCE(4), SCE(5));
      u32 x67 = cvtpk(SCE(6), SCE(7));
      #undef SCE
      u32x2 r02 = __builtin_amdgcn_permlane32_swap(x01, x45, false, false);
      u32x2 r13 = __builtin_amdgcn_permlane32_swap(x23, x67, false, false);
      FragU f;
      f.u[0] = r02.x; f.u[1] = r13.x; f.u[2] = r02.y; f.u[3] = r13.y;
      pf[kt] = f.v;
    }

    __builtin_amdgcn_s_setprio(1);

    // (5) QK(i+1) into accS (overlaps this iter's VALU)
    if (i < NSTEPS-1){
      #pragma unroll
      for (int h2=0;h2<2;++h2){
        accS[h2] = __builtin_amdgcn_mfma_f32_32x32x16_bf16(
                     *(const s16x8*)(kbn + (h2*4+0)*1024), qf[0], z16, 0, 0, 0);
        #pragma unroll
        for (int dt=1;dt<4;++dt)
          accS[h2] = __builtin_amdgcn_mfma_f32_32x32x16_bf16(
                       *(const s16x8*)(kbn + (h2*4+dt)*1024), qf[dt], accS[h2], 0, 0, 0);
      }
    }

    // (6) PV(i)
    #pragma unroll
    for (int mt=0;mt<2;++mt){
      #pragma unroll
      for (int kt=0;kt<4;++kt){
        s16x8 vf = *(const s16x8*)(vbc + (mt*4+kt)*1024);
        accO[mt] = __builtin_amdgcn_mfma_f32_32x32x16_bf16(vf, pf[kt], accO[mt], 0, 0, 0);
      }
    }

    __builtin_amdgcn_s_setprio(0);

    // (7) all this iter's LDS reads retired -> next iter may overwrite buffers
    WAITLG0();
    __builtin_amdgcn_s_barrier();
  }

  lsum += __shfl_xor(lsum, 32, 64);
  const float inv = 1.0f / lsum;
  float* ob = outg + ((size_t)b*S_LEN + qrow)*EMB + h*DK;
  #pragma unroll
  for (int mt=0;mt<2;++mt){
    #pragma unroll
    for (int u=0;u<4;++u){
      f32x4 w;
      #pragma unroll
      for (int e=0;e<4;++e) w[e] = accO[mt][u*4+e]*inv;
      *(f32x4*)(ob + mt*32 + u*8 + hi*4) = w;
    }
  }
}

// ================== fallback (Round-2 kernel, used if ws too small) ==================
__global__ __launch_bounds__(256)
void mha_fwd_fb(const float* __restrict__ qg, const float* __restrict__ kg,
                const float* __restrict__ vg, const int* __restrict__ maskg,
                float* __restrict__ outg)
{
  __shared__ __align__(16) unsigned char sK [2][KVB*128];
  __shared__ __align__(16) unsigned char sVt[2][DK*128];
  __shared__ float sBias[2][KVB];
  __shared__ int sAllOne;

  const int i0  = blockIdx.x;
  const int xcd = i0 & 7;
  const int jj0 = i0 >> 3;
  const int bh  = (xcd << 3) | (jj0 >> 4);
  const int qt  = jj0 & 15;
  const int b   = bh >> 4;
  const int h   = bh & 15;

  const int tid  = threadIdx.x;
  const int lane = tid & 63;
  const int wave = tid >> 6;
  const int l31  = lane & 31;
  const int hi   = lane >> 5;

  if (tid == 0) sAllOne = 1;
  __syncthreads();
  {
    int ok = 1;
    for (int i = tid; i < S_LEN; i += 256) ok &= (maskg[(size_t)b*S_LEN + i] != 0);
    if (!ok) atomicAnd(&sAllOne, 0);
  }

  const float QSCALE = 0.18033688011112042f;
  const int qrow = qt*128 + wave*32 + l31;
  const float* qb = qg + ((size_t)b*S_LEN + qrow)*EMB + h*DK + hi*8;
  s16x8 qf[4];
  #pragma unroll
  for (int dt=0; dt<4; ++dt){
    f32x4 a = *(const f32x4*)(qb + dt*16);
    f32x4 c = *(const f32x4*)(qb + dt*16 + 4);
    FragU f;
    f.u[0] = cvtpk(a[0]*QSCALE, a[1]*QSCALE);
    f.u[1] = cvtpk(a[2]*QSCALE, a[3]*QSCALE);
    f.u[2] = cvtpk(c[0]*QSCALE, c[1]*QSCALE);
    f.u[3] = cvtpk(c[2]*QSCALE, c[3]*QSCALE);
    qf[dt] = f.v;
  }

  const int srow = tid >> 2;
  const int sc4  = (tid & 3) << 4;
  const int vcg = tid & 15;
  const int vrg = tid >> 4;

  const float* kg_b = kg + (size_t)b*S_LEN*EMB + h*DK;
  const float* vg_b = vg + (size_t)b*S_LEN*EMB + h*DK;
  const float* kp0 = kg_b + (size_t)srow*EMB + sc4;
  const float* vp0 = vg_b + (size_t)(vrg*4)*EMB + vcg*4;

  f32x4 kr[4], vr[4];
  float biasr = 0.f;

  auto stage_load = [&](int t, bool needMask){
    const float* kp = kp0 + (size_t)t*(KVB*EMB);
    const float* vp = vp0 + (size_t)t*(KVB*EMB);
    #pragma unroll
    for (int i=0;i<4;++i) kr[i] = *(const f32x4*)(kp + 4*i);
    #pragma unroll
    for (int e=0;e<4;++e) vr[e] = *(const f32x4*)(vp + (size_t)e*EMB);
    if (needMask && tid < KVB)
      biasr = (maskg[(size_t)b*S_LEN + t*KVB + tid] != 0) ? 0.f : -1.0e9f;
  };

  auto stage_write = [&](int buf, bool needMask){
    unsigned char* kd = sK[buf] + srow*128;
    const u32 kswz = (u32)(srow & 7) << 4;
    u32x4 w0, w1;
    w0.x = cvtpk(kr[0][0],kr[0][1]); w0.y = cvtpk(kr[0][2],kr[0][3]);
    w0.z = cvtpk(kr[1][0],kr[1][1]); w0.w = cvtpk(kr[1][2],kr[1][3]);
    w1.x = cvtpk(kr[2][0],kr[2][1]); w1.y = cvtpk(kr[2][2],kr[2][3]);
    w1.z = cvtpk(kr[3][0],kr[3][1]); w1.w = cvtpk(kr[3][2],kr[3][3]);
    *(u32x4*)(kd + (((u32)(sc4*2))      ^ kswz)) = w0;
    *(u32x4*)(kd + (((u32)(sc4*2 + 16)) ^ kswz)) = w1;
    unsigned char* vd = sVt[buf];
    #pragma unroll
    for (int j=0;j<4;++j){
      const int d = vcg*4 + j;
      u32x2 w;
      w.x = cvtpk(vr[0][j], vr[1][j]);
      w.y = cvtpk(vr[2][j], vr[3][j]);
      const u32 swz = (u32)(((d & 7) ^ ((d >> 3) & 1)) << 4);
      *(u32x2*)(vd + d*128 + (((u32)(vrg*8)) ^ swz)) = w;
    }
    if (needMask && tid < KVB) sBias[buf][tid] = biasr;
  };

  f32x16 accO[2];
  #pragma unroll
  for (int mt=0;mt<2;++mt)
    #pragma unroll
    for (int r=0;r<16;++r) accO[mt][r] = 0.f;
  float mrun = -1.0e30f, lrun = 0.f;

  stage_load(0, true);
  stage_write(0, true);
  __syncthreads();
  const bool allone = (sAllOne != 0);

  for (int t=0; t<NSTEPS; ++t){
    const int cur = t & 1;
    if (t+1 < NSTEPS) stage_load(t+1, !allone);

    f32x16 accS[2];
    #pragma unroll
    for (int h2=0;h2<2;++h2)
      #pragma unroll
      for (int r=0;r<16;++r) accS[h2][r] = 0.f;

    const u32 kvswz = (u32)(l31 & 7) << 4;
    #pragma unroll
    for (int h2=0;h2<2;++h2){
      const unsigned char* krow = sK[cur] + (h2*32 + l31)*128;
      #pragma unroll
      for (int dt=0;dt<4;++dt){
        s16x8 kf = *(const s16x8*)(krow + (((u32)(dt*32 + hi*16)) ^ kvswz));
        accS[h2] = __builtin_amdgcn_mfma_f32_32x32x16_bf16(kf, qf[dt], accS[h2], 0, 0, 0);
      }
    }

    if (!allone){
      #pragma unroll
      for (int h2=0;h2<2;++h2)
        #pragma unroll
        for (int r=0;r<16;++r){
          const int kv = h2*32 + (r&3) + 8*(r>>2) + 4*hi;
          accS[h2][r] += sBias[cur][kv];
        }
    }

    float pmax = fmaxf(accS[0][0], accS[1][0]);
    #pragma unroll
    for (int r=1;r<16;++r) pmax = fmaxf(pmax, fmaxf(accS[0][r], accS[1][r]));
    pmax = fmaxf(pmax, __shfl_xor(pmax, 32, 64));

    if (!__all(pmax - mrun <= 8.0f)){
      const float mnew  = fmaxf(mrun, pmax);
      const float alpha = EXP2(mrun - mnew);
      lrun *= alpha;
      #pragma unroll
      for (int mt=0;mt<2;++mt)
        #pragma unroll
        for (int r=0;r<16;++r) accO[mt][r] *= alpha;
      mrun = mnew;
    }

    float rsum = 0.f;
    #pragma unroll
    for (int h2=0;h2<2;++h2)
      #pragma unroll
      for (int r=0;r<16;++r){
        float p = EXP2(accS[h2][r] - mrun);
        accS[h2][r] = p;
        rsum += p;
      }
    rsum += __shfl_xor(rsum, 32, 64);
    lrun += rsum;

    s16x8 pf[4];
    #pragma unroll
    for (int kt=0;kt<4;++kt){
      #define SCE(j) accS[(kt)>>1][((kt)&1)*8 + (j)]
      u32 x01 = cvtpk(SCE(0), SCE(1));
      u32 x23 = cvtpk(SCE(2), SCE(3));
      u32 x45 = cvtpk(SCE(4), SCE(5));
      u32 x67 = cvtpk(SCE(6), SCE(7));
      #undef SCE
      u32x2 r02 = __builtin_amdgcn_permlane32_swap(x01, x45, false, false);
      u32x2 r13 = __builtin_amdgcn_permlane32_swap(x23, x67, false, false);
      FragU f;
      f.u[0] = r02.x; f.u[1] = r13.x; f.u[2] = r02.y; f.u[3] = r13.y;
      pf[kt] = f.v;
    }

    #pragma unroll
    for (int mt=0;mt<2;++mt){
      const int vrow = mt*32 + l31;
      const u32 vswz = (u32)((((vrow & 7) ^ ((vrow >> 3) & 1))) << 4);
      const unsigned char* vrp = sVt[cur] + vrow*128;
      #pragma unroll
      for (int kt=0;kt<4;++kt){
        s16x8 vf = *(const s16x8*)(vrp + (((u32)(kt*32 + hi*16)) ^ vswz));
        accO[mt] = __builtin_amdgcn_mfma_f32_32x32x16_bf16(vf, pf[kt], accO[mt], 0, 0, 0);
      }
    }

    if (t+1 < NSTEPS) stage_write(cur^1, !allone);
    __syncthreads();
  }

  const float inv = 1.0f / lrun;
  float* ob = outg + ((size_t)b*S_LEN + qrow)*EMB + h*DK;
  #pragma unroll
  for (int mt=0;mt<2;++mt){
    #pragma unroll
    for (int u=0;u<4;++u){
      f32x4 w;
      #pragma unroll
      for (int e=0;e<4;++e) w[e] = accO[mt][u*4+e]*inv;
      *(f32x4*)(ob + mt*32 + u*8 + hi*4) = w;
    }
  }
}

extern "C" void kernel_launch(void* const* d_in, const int* in_sizes, int n_in,
                              void* d_out, int out_size, void* d_ws, size_t ws_size,
                              hipStream_t stream)
{
  const float* q    = (const float*)d_in[0];
  const float* k    = (const float*)d_in[1];
  const float* v    = (const float*)d_in[2];
  const int*   mask = (const int*)d_in[3];
  float* out = (float*)d_out;
  (void)in_sizes; (void)n_in; (void)out_size;

  if (ws_size >= 2*KVBYTES){
    unsigned char* gK = (unsigned char*)d_ws;
    unsigned char* gV = gK + KVBYTES;
    hipLaunchKernelGGL(prep_kv, dim3(4*NHEAD*NSTEPS), dim3(256), 0, stream, k, v, gK, gV);
    hipLaunchKernelGGL(mha_main, dim3(64*QTILES), dim3(256), 0, stream, q, mask, gK, gV, out);
  } else {
    hipLaunchKernelGGL(mha_fwd_fb, dim3(64*QTILES), dim3(256), 0, stream, q, k, v, mask, out);
  }
}